// Round 15
// baseline (476.376 us; speedup 1.0000x reference)
//
#include <hip/hip_runtime.h>
#include <math.h>

// GConvLSTM single step from zero state + linear head.
// H=C=0 initially => cheb_conv(H)=bh[g], F-gate irrelevant.
//   I = sigmoid(chebX_0 + b*), T = tanh(chebX_2 + b*), C = I*T,
//   O = sigmoid(chebX_3 + b* + wc2*C), out = (O*tanh(C)) @ lin_w + lin_b
//
// R2 pull-CSR; R3 hw transcendentals; R7 zero global atomics;
// R8 bf16 MFMA; R9 bf16 recursion; R10 fused gather3; R11 full-CU scans;
// R12 merged scan w/ atomic barrier; R13 operand-split front; R14 fill revert.
// R15: 3-kernel pipeline. K2 = scan+fill (2 in-kernel grid barriers),
//      K3 = gather1+gather2+final (2 barriers). Dispatches 8 -> 4;
//      ~20us of launch gaps replaced by ~2us of flag-spin barriers
//      (pattern HW-proven in R12's k_scan_merged).

#define NT 256
#define NCH 64      // edge chunks
#define RSD 25600   // deg hist range: 25600*4B = 100KB LDS
#define RSF 20480   // fill range: 80KB LDS
#define G2 (3 * NCH)   // 192 blocks (fill shape)
#define G3 256
#define NT3 512

typedef __attribute__((ext_vector_type(8))) short short8v;
typedef __attribute__((ext_vector_type(8))) unsigned short ushort8v;
typedef __attribute__((ext_vector_type(4))) float f32x4;

__device__ __forceinline__ short f2bf(float f) {
    unsigned u = __float_as_uint(f);
    u += 0x7FFFu + ((u >> 16) & 1u);   // round-to-nearest-even
    return (short)(u >> 16);
}
__device__ __forceinline__ float bf2f(unsigned short b) {
    return __uint_as_float((unsigned)b << 16);
}

// grid barrier: all prior writes flushed (threadfence), arrive, spin, inv.
__device__ __forceinline__ void gbar(int* flag, int target) {
    __syncthreads();
    if (threadIdx.x == 0) {
        __threadfence();
        __hip_atomic_fetch_add(flag, 1, __ATOMIC_ACQ_REL, __HIP_MEMORY_SCOPE_AGENT);
        while (__hip_atomic_load(flag, __ATOMIC_ACQUIRE,
                                 __HIP_MEMORY_SCOPE_AGENT) < target)
            __builtin_amdgcn_s_sleep(2);
    }
    __syncthreads();
    __threadfence();
}

// K1: role A (bid < degB): deg f32 LDS histogram (2 ranges x 64 chunks).
// role B (next 64): cnt u16-packed whole-N histogram. role C: prepack + xb.
__global__ __launch_bounds__(1024)
void k_front(const int* __restrict__ src, const int* __restrict__ dst,
             const float* __restrict__ w, float* __restrict__ degPart,
             unsigned short* __restrict__ cntPart,
             const float* __restrict__ Wx, short* __restrict__ P,
             const float* __restrict__ x, short* __restrict__ xb,
             int nE, int N, int degB, int n4) {
    __shared__ unsigned smem[RSD];   // 100KB, role-dependent view
    const int bid = blockIdx.x;
    const int chunk = (nE + NCH - 1) / NCH;

    if (bid < degB) {                       // ---- deg histogram ----
        float* s_deg = reinterpret_cast<float*>(smem);
        const int r = bid / NCH, b = bid % NCH;
        const int base = r * RSD;
        for (int i = threadIdx.x; i < RSD; i += 1024) s_deg[i] = 0.f;
        __syncthreads();
        const int e0 = b * chunk, e1 = min(e0 + chunk, nE);
        for (int e = e0 + (int)threadIdx.x; e < e1; e += 1024) {
            unsigned so = (unsigned)(src[e] - base);
            if (so < RSD) atomicAdd(&s_deg[so], w[e]);
        }
        __syncthreads();
        const int lim = min(RSD, N - base);
        for (int i = threadIdx.x; i < lim; i += 1024)
            degPart[(size_t)b * N + base + i] = s_deg[i];
        return;
    }
    if (bid < degB + NCH) {                 // ---- cnt histogram (whole N) ----
        unsigned* s_cnt2 = smem;
        const int b = bid - degB;
        const int pairsN = (N + 1) >> 1;
        for (int i = threadIdx.x; i < pairsN; i += 1024) s_cnt2[i] = 0u;
        __syncthreads();
        const int e0 = b * chunk, e1 = min(e0 + chunk, nE);
        for (int e = e0 + (int)threadIdx.x; e < e1; e += 1024) {
            unsigned d = (unsigned)dst[e];
            atomicAdd(&s_cnt2[d >> 1], 1u << ((d & 1) * 16));
        }
        __syncthreads();
        unsigned* cp32 = reinterpret_cast<unsigned*>(cntPart + (size_t)b * N);
        for (int i = threadIdx.x; i < pairsN; i += 1024) cp32[i] = s_cnt2[i];
        return;
    }
    // ---- prepack + x->bf16 ----
    int idx = (bid - degB - NCH) * 1024 + (int)threadIdx.x;
    if (idx < 12 * 4 * 64) {
        int lane = idx & 63;
        int kt = (idx >> 6) & 3;
        int nt = idx >> 8;
        int gate = (nt < 4) ? 0 : (nt < 8) ? 2 : 3;
        int h = (nt & 3) * 16 + (lane & 15);
        int fb = (lane >> 4) * 8;
        short8v v;
#pragma unroll
        for (int j = 0; j < 8; ++j)
            v[j] = f2bf(Wx[((size_t)(gate * 4 + kt) * 32 + fb + j) * 64 + h]);
        *(reinterpret_cast<short8v*>(P) + idx) = v;
        return;
    }
    int i = idx - 12 * 4 * 64;
    if (i >= n4) return;
    const float4 v = *reinterpret_cast<const float4*>(x + (size_t)i * 4);
    short4 rb;
    rb.x = f2bf(v.x); rb.y = f2bf(v.y); rb.z = f2bf(v.z); rb.w = f2bf(v.w);
    *reinterpret_cast<short4*>(xb + (size_t)i * 4) = rb;
}

// K2: scan (blocks 0..nbS-1, 2048 nodes each) -> B1 -> prefix+rowptr+offs
// -> B2 -> fill (all 192 blocks, 3 ranges x 64 chunks, LDS cursor).
__global__ __launch_bounds__(1024)
void k_scan_fill(const float* __restrict__ degPart,
                 const unsigned short* __restrict__ cntPart,
                 float* __restrict__ dinv, int* __restrict__ cnt,
                 int* __restrict__ rowptr, int* __restrict__ partials,
                 int* __restrict__ flag, int* __restrict__ offs,
                 const int* __restrict__ src, const int* __restrict__ dst,
                 const float* __restrict__ w, int2* __restrict__ entries,
                 int nE, int N) {
    __shared__ int smem[RSF];   // 80KB; scan phase uses [0..1023]
    const int t = threadIdx.x;
    const int bid = blockIdx.x;
    const int nbS = (N + 2047) / 2048;
    const int n0 = bid * 2048 + t * 2;

    // ---- phase 1: per-node reduce + block-local exclusive scan ----
    int c0 = 0, c1 = 0, ex = 0;
    if (bid < nbS) {
        float d0 = 0.f, d1 = 0.f;
        if (n0 < N) {
#pragma unroll 8
            for (int b = 0; b < NCH; ++b) {
                const float2 dv = *reinterpret_cast<const float2*>(degPart + (size_t)b * N + n0);
                d0 += dv.x; d1 += dv.y;
                unsigned cc = *reinterpret_cast<const unsigned*>(cntPart + (size_t)b * N + n0);
                c0 += (int)(cc & 0xFFFFu); c1 += (int)(cc >> 16);
            }
            dinv[n0] = d0 > 0.f ? rsqrtf(d0) : 0.f;
            cnt[n0] = c0;
            if (n0 + 1 < N) {
                dinv[n0 + 1] = d1 > 0.f ? rsqrtf(d1) : 0.f;
                cnt[n0 + 1] = c1;
            } else c1 = 0;
        }
        int cs = c0 + c1;
        smem[t] = cs;
        __syncthreads();
        for (int off = 1; off < 1024; off <<= 1) {
            int u = (t >= off) ? smem[t - off] : 0;
            __syncthreads();
            smem[t] += u;
            __syncthreads();
        }
        ex = smem[t] - cs;
        if (t == 1023)
            __hip_atomic_store(&partials[bid], smem[1023], __ATOMIC_RELEASE,
                               __HIP_MEMORY_SCOPE_AGENT);
    }
    gbar(flag, G2);

    // ---- phase 2: per-block prefix + rowptr + per-chunk offs ----
    if (bid < nbS) {
        int v = (t < bid) ? __hip_atomic_load(&partials[t], __ATOMIC_ACQUIRE,
                                              __HIP_MEMORY_SCOPE_AGENT)
                          : 0;
        smem[t] = v;
        __syncthreads();
        for (int off = 512; off > 0; off >>= 1) {
            if (t < off) smem[t] += smem[t + off];
            __syncthreads();
        }
        const int prefix = smem[0];
        if (n0 < N) {
            const bool has1 = (n0 + 1) < N;
            int s0 = ex + prefix;
            int s1 = has1 ? ex + c0 + prefix : 0;
            rowptr[n0] = s0;
            if (has1) rowptr[n0 + 1] = s1;
#pragma unroll 8
            for (int b = 0; b < NCH; ++b) {
                unsigned cc = *reinterpret_cast<const unsigned*>(cntPart + (size_t)b * N + n0);
                if (has1) {
                    *reinterpret_cast<int2*>(offs + (size_t)b * N + n0) = make_int2(s0, s1);
                } else {
                    offs[(size_t)b * N + n0] = s0;
                }
                s0 += (int)(cc & 0xFFFFu);
                s1 += (int)(cc >> 16);
            }
        }
    }
    gbar(flag, 2 * G2);

    // ---- phase 3: counting-sort fill ----
    const int r = bid / NCH, b = bid % NCH;
    const int base = r * RSF;
    const int lim = min(RSF, N - base);
    for (int i = t; i < lim; i += 1024)
        smem[i] = offs[(size_t)b * N + base + i];
    __syncthreads();
    const int chunk = (nE + NCH - 1) / NCH;
    const int e0 = b * chunk, e1 = min(e0 + chunk, nE);
    for (int e = e0 + t; e < e1; e += 1024) {
        int d = dst[e];
        unsigned dof = (unsigned)(d - base);
        if (dof < RSF) {
            int s = src[e];
            float nv = -dinv[s] * w[e] * dinv[d];
            int pos = atomicAdd(&smem[dof], 1);
            entries[pos] = make_int2(s, __float_as_int(nv));
        }
    }
}

__device__ __forceinline__ void bf8_fma(float* acc, ushort8v v, float s) {
#pragma unroll
    for (int j = 0; j < 8; ++j)
        acc[j] = fmaf(s, bf2f(v[j]), acc[j]);
}

// one gather work-item: 16 threads/node (tq feature-slice, qr entry-quarter)
__device__ __forceinline__ void gather_item(
    const unsigned short* __restrict__ tb, const unsigned short* __restrict__ subb,
    short* __restrict__ outb, const int* __restrict__ rowptr,
    const int* __restrict__ cnt, const int2* __restrict__ entries,
    float scale, int idx) {
    int n = idx >> 4, tq = idx & 3, qr = (idx >> 2) & 3;
    int beg = rowptr[n], end = beg + cnt[n];
    float acc0[8] = {0, 0, 0, 0, 0, 0, 0, 0};
    float acc1[8] = {0, 0, 0, 0, 0, 0, 0, 0};
    int i = beg + qr;
    for (; i + 12 < end; i += 16) {
        int2 e0 = entries[i];
        int2 e1 = entries[i + 4];
        int2 e2 = entries[i + 8];
        int2 e3 = entries[i + 12];
        ushort8v v0 = *reinterpret_cast<const ushort8v*>(tb + (size_t)e0.x * 32 + tq * 8);
        ushort8v v1 = *reinterpret_cast<const ushort8v*>(tb + (size_t)e1.x * 32 + tq * 8);
        ushort8v v2 = *reinterpret_cast<const ushort8v*>(tb + (size_t)e2.x * 32 + tq * 8);
        ushort8v v3 = *reinterpret_cast<const ushort8v*>(tb + (size_t)e3.x * 32 + tq * 8);
        bf8_fma(acc0, v0, __int_as_float(e0.y));
        bf8_fma(acc1, v1, __int_as_float(e1.y));
        bf8_fma(acc0, v2, __int_as_float(e2.y));
        bf8_fma(acc1, v3, __int_as_float(e3.y));
    }
    for (; i < end; i += 4) {
        int2 e0 = entries[i];
        ushort8v v0 = *reinterpret_cast<const ushort8v*>(tb + (size_t)e0.x * 32 + tq * 8);
        bf8_fma(acc0, v0, __int_as_float(e0.y));
    }
    float r[8];
#pragma unroll
    for (int j = 0; j < 8; ++j) {
        r[j] = acc0[j] + acc1[j];
        r[j] += __shfl_xor(r[j], 4);
        r[j] += __shfl_xor(r[j], 8);
    }
    if (qr == 0) {
        if (subb) {
            ushort8v sv = *reinterpret_cast<const ushort8v*>(subb + (size_t)n * 32 + tq * 8);
#pragma unroll
            for (int j = 0; j < 8; ++j) r[j] = fmaf(scale, r[j], -bf2f(sv[j]));
        } else {
#pragma unroll
            for (int j = 0; j < 8; ++j) r[j] *= scale;
        }
        short8v rb;
#pragma unroll
        for (int j = 0; j < 8; ++j) rb[j] = f2bf(r[j]);
        *reinterpret_cast<short8v*>(outb + (size_t)n * 32 + tq * 8) = rb;
    }
}

__device__ __forceinline__ float sigf(float x) {
    return __builtin_amdgcn_rcpf(1.f + __builtin_amdgcn_exp2f(-1.4426950408889634f * x));
}
__device__ __forceinline__ float tanhf_fast(float x) {
    float e = __builtin_amdgcn_exp2f(2.8853900817779268f * x);
    return 1.f - 2.f * __builtin_amdgcn_rcpf(e + 1.f);
}

// K3: gather1 -> B1 -> gather2 -> B2 -> fused gather3+MFMA+LSTM+head.
// 256 blocks x 512 threads (co-resident), grid-stride; shuffle groups stay
// wave-local (stride multiple of 16; N*16 boundary multiple of 16).
__global__ __launch_bounds__(NT3)
void k_gather_final(const short* __restrict__ xb, short* __restrict__ Tx1b,
                    short* __restrict__ Tx2b, const short* __restrict__ P,
                    const int* __restrict__ rowptr, const int* __restrict__ cnt,
                    const int2* __restrict__ entries,
                    const float* __restrict__ bx, const float* __restrict__ bh,
                    const float* __restrict__ wc, const float* __restrict__ bg,
                    const float* __restrict__ lin_w, const float* __restrict__ lin_b,
                    int* __restrict__ flag, float* __restrict__ out, int N) {
    const int stride = G3 * NT3;
    const int tid0 = blockIdx.x * NT3 + (int)threadIdx.x;
    const unsigned short* xbu = reinterpret_cast<const unsigned short*>(xb);

    // phase 1: Tx1b = prop(x)
    for (int idx = tid0; idx < N * 16; idx += stride)
        gather_item(xbu, nullptr, Tx1b, rowptr, cnt, entries, 1.f, idx);
    gbar(flag, G3);

    // phase 2: Tx2b = 2*prop(Tx1b) - x
    for (int idx = tid0; idx < N * 16; idx += stride)
        gather_item(reinterpret_cast<const unsigned short*>(Tx1b), xbu, Tx2b,
                    rowptr, cnt, entries, 2.f, idx);
    gbar(flag, 2 * G3);

    // phase 3: fused gather3 + MFMA gates + LSTM pointwise + linear head
    const int wave = (int)threadIdx.x >> 6, lane = (int)threadIdx.x & 63;
    const unsigned short* t2b = reinterpret_cast<const unsigned short*>(Tx2b);
    const int nTiles = (N + 127) / 128;
    for (int tile = blockIdx.x; tile < nTiles; tile += G3) {
        const int nb = tile * 128 + wave * 16;
        const int rc = min(nb + (lane & 15), N - 1);
        const int ko = (lane >> 4) * 8;

        int beg = rowptr[rc], end = beg + cnt[rc];
        float acc0[8] = {0, 0, 0, 0, 0, 0, 0, 0};
        float acc1[8] = {0, 0, 0, 0, 0, 0, 0, 0};
        int i = beg;
        for (; i + 3 < end; i += 4) {
            int2 e0 = entries[i];
            int2 e1 = entries[i + 1];
            int2 e2 = entries[i + 2];
            int2 e3 = entries[i + 3];
            ushort8v v0 = *reinterpret_cast<const ushort8v*>(t2b + (size_t)e0.x * 32 + ko);
            ushort8v v1 = *reinterpret_cast<const ushort8v*>(t2b + (size_t)e1.x * 32 + ko);
            ushort8v v2 = *reinterpret_cast<const ushort8v*>(t2b + (size_t)e2.x * 32 + ko);
            ushort8v v3 = *reinterpret_cast<const ushort8v*>(t2b + (size_t)e3.x * 32 + ko);
            bf8_fma(acc0, v0, __int_as_float(e0.y));
            bf8_fma(acc1, v1, __int_as_float(e1.y));
            bf8_fma(acc0, v2, __int_as_float(e2.y));
            bf8_fma(acc1, v3, __int_as_float(e3.y));
        }
        for (; i < end; ++i) {
            int2 e0 = entries[i];
            ushort8v v0 = *reinterpret_cast<const ushort8v*>(t2b + (size_t)e0.x * 32 + ko);
            bf8_fma(acc0, v0, __int_as_float(e0.y));
        }

        short8v A0 = *reinterpret_cast<const short8v*>(xb   + (size_t)rc * 32 + ko);
        short8v A1 = *reinterpret_cast<const short8v*>(Tx1b + (size_t)rc * 32 + ko);
        short8v A2 = *reinterpret_cast<const short8v*>(Tx2b + (size_t)rc * 32 + ko);
        short8v A3;
#pragma unroll
        for (int j = 0; j < 8; ++j)   // Tx3 = 2*prop(Tx2) - Tx1
            A3[j] = f2bf(2.f * (acc0[j] + acc1[j]) - bf2f((unsigned short)A1[j]));

        const short8v* Pv = reinterpret_cast<const short8v*>(P);
        f32x4 acc[12];
#pragma unroll
        for (int nt = 0; nt < 12; ++nt) {
            const short8v* Pb = Pv + (size_t)nt * 4 * 64 + lane;
            f32x4 a = {0.f, 0.f, 0.f, 0.f};
            a = __builtin_amdgcn_mfma_f32_16x16x32_bf16(A0, Pb[0],   a, 0, 0, 0);
            a = __builtin_amdgcn_mfma_f32_16x16x32_bf16(A1, Pb[64],  a, 0, 0, 0);
            a = __builtin_amdgcn_mfma_f32_16x16x32_bf16(A2, Pb[128], a, 0, 0, 0);
            a = __builtin_amdgcn_mfma_f32_16x16x32_bf16(A3, Pb[192], a, 0, 0, 0);
            acc[nt] = a;
        }

        const int hq = lane & 15;
        const int ng = lane >> 4;
        const float lb = lin_b[0];
        float p[4] = {0.f, 0.f, 0.f, 0.f};
#pragma unroll
        for (int ht = 0; ht < 4; ++ht) {
            int h = ht * 16 + hq;
            float bI = bx[h] + bh[h] + bg[h];
            float bC = bx[128 + h] + bh[128 + h] + bg[128 + h];
            float bO = bx[192 + h] + bh[192 + h] + bg[192 + h];
            float w2 = wc[128 + h];
            float lw = lin_w[h];
#pragma unroll
            for (int r = 0; r < 4; ++r) {
                float I = sigf(acc[ht][r] + bI);
                float T = tanhf_fast(acc[4 + ht][r] + bC);
                float C = I * T;
                float O = sigf(acc[8 + ht][r] + bO + w2 * C);
                float H = O * tanhf_fast(C);
                p[r] = fmaf(H, lw, p[r]);
            }
        }
#pragma unroll
        for (int r = 0; r < 4; ++r) {
            float v = p[r];
            v += __shfl_xor(v, 1);
            v += __shfl_xor(v, 2);
            v += __shfl_xor(v, 4);
            v += __shfl_xor(v, 8);
            if (hq == 0) {
                int n = nb + ng * 4 + r;
                if (n < N) out[n] = v + lb;
            }
        }
    }
}

extern "C" void kernel_launch(void* const* d_in, const int* in_sizes, int n_in,
                              void* d_out, int out_size, void* d_ws, size_t ws_size,
                              hipStream_t stream) {
    const float* x   = (const float*)d_in[0];
    const int*   ei  = (const int*)d_in[1];
    const float* ew  = (const float*)d_in[2];
    const float* Wx  = (const float*)d_in[3];
    const float* bx  = (const float*)d_in[4];
    // d_in[5] = Wh (unused: zero initial state)
    const float* bh  = (const float*)d_in[6];
    const float* wcp = (const float*)d_in[7];
    const float* bg  = (const float*)d_in[8];
    const float* lw  = (const float*)d_in[9];
    const float* lb  = (const float*)d_in[10];
    float* out = (float*)d_out;

    const int N  = in_sizes[0] / 32;
    const int nE = in_sizes[2];
    const int* src = ei;
    const int* dst = ei + nE;

    char* ws = (char*)d_ws;
    size_t off = 0;
    float* dinv    = (float*)(ws + off); off += (size_t)N * 4;
    int*   cnt     = (int*)(ws + off);   off += (size_t)N * 4;
    int*   rowptr  = (int*)(ws + off);   off += (size_t)N * 4;
    int*   partials= (int*)(ws + off);   off += 1024 * 4;
    int*   flags   = (int*)(ws + off);   off += 256;   // flags[0]=K2, flags[1]=K3
    short* P       = (short*)(ws + off); off += 12 * 4 * 64 * 8 * 2;
    int2*  entries = (int2*)(ws + off);  off += (size_t)nE * 8;
    float* degPart = (float*)(ws + off); off += (size_t)NCH * N * 4;  // aliased as offs
    unsigned short* cntPart = (unsigned short*)(ws + off); off += (size_t)NCH * N * 2;
    short* xbuf    = (short*)(ws + off); off += (size_t)N * 32 * 2;
    short* Tx1b    = (short*)(ws + off); off += (size_t)N * 32 * 2;
    short* Tx2b    = (short*)(ws + off); off += (size_t)N * 32 * 2;

    int* offs = (int*)degPart;  // degPart dead after K2 phase 1

    const int nRangeD = (N + RSD - 1) / RSD;
    const int degB = nRangeD * NCH;
    const int n4 = N * 8;
    const int xbB = (12 * 4 * 64 + n4 + 1023) / 1024;

    hipMemsetAsync(flags, 0, 8, stream);
    k_front<<<degB + NCH + xbB, 1024, 0, stream>>>(src, dst, ew, degPart, cntPart,
                                                   Wx, P, x, xbuf, nE, N, degB, n4);
    k_scan_fill<<<G2, 1024, 0, stream>>>(degPart, cntPart, dinv, cnt, rowptr,
                                         partials, &flags[0], offs, src, dst, ew,
                                         entries, nE, N);
    k_gather_final<<<G3, NT3, 0, stream>>>(xbuf, Tx1b, Tx2b, P, rowptr, cnt,
                                           entries, bx, bh, wcp, bg, lw, lb,
                                           &flags[1], out, N);
}

// Round 16
// 191.206 us; speedup vs baseline: 2.4914x; 2.4914x over previous
//
#include <hip/hip_runtime.h>
#include <math.h>

// GConvLSTM single step from zero state + linear head.
// H=C=0 initially => cheb_conv(H)=bh[g], F-gate irrelevant.
//   I = sigmoid(chebX_0 + b*), T = tanh(chebX_2 + b*), C = I*T,
//   O = sigmoid(chebX_3 + b* + wc2*C), out = (O*tanh(C)) @ lin_w + lin_b
//
// R2 pull-CSR; R3 hw transcendentals; R7 zero global atomics;
// R8 bf16 MFMA; R9 bf16 recursion; R10 fused gather3; R11 full-CU scans;
// R12 merged scan w/ atomic barrier; R13/R14 operand-split front + fill.
// R15 (FAILED, 476us): per-thread __threadfence + acquire-per-spin-iter
//      flooded agent-scope L2 wb/inv ops.
// R16: cheap barrier -- release-add by thread0, RELAXED spin + s_sleep,
//      ONE acquire fence on exit. ~2 cache ops/block/barrier total.

#define NT 256
#define NCH 64      // edge chunks
#define RSD 25600   // deg hist range: 25600*4B = 100KB LDS
#define RSF 20480   // fill range: 80KB LDS
#define G2 (3 * NCH)   // 192 blocks (fill shape)
#define G3 256
#define NT3 512

typedef __attribute__((ext_vector_type(8))) short short8v;
typedef __attribute__((ext_vector_type(8))) unsigned short ushort8v;
typedef __attribute__((ext_vector_type(4))) float f32x4;

__device__ __forceinline__ short f2bf(float f) {
    unsigned u = __float_as_uint(f);
    u += 0x7FFFu + ((u >> 16) & 1u);   // round-to-nearest-even
    return (short)(u >> 16);
}
__device__ __forceinline__ float bf2f(unsigned short b) {
    return __uint_as_float((unsigned)b << 16);
}

// grid barrier, cheap form: one release-add + relaxed spin + one acquire
// fence per BLOCK (not per thread, not per spin iteration).
__device__ __forceinline__ void gbar(int* flag, int target) {
    __syncthreads();
    if (threadIdx.x == 0) {
        __hip_atomic_fetch_add(flag, 1, __ATOMIC_RELEASE, __HIP_MEMORY_SCOPE_AGENT);
        while (__hip_atomic_load(flag, __ATOMIC_RELAXED,
                                 __HIP_MEMORY_SCOPE_AGENT) < target)
            __builtin_amdgcn_s_sleep(8);
        __builtin_amdgcn_fence(__ATOMIC_ACQUIRE, "agent");
    }
    __syncthreads();
}

// K1: role A (bid < degB): deg f32 LDS histogram (2 ranges x 64 chunks).
// role B (next 64): cnt u16-packed whole-N histogram. role C: prepack + xb.
__global__ __launch_bounds__(1024)
void k_front(const int* __restrict__ src, const int* __restrict__ dst,
             const float* __restrict__ w, float* __restrict__ degPart,
             unsigned short* __restrict__ cntPart,
             const float* __restrict__ Wx, short* __restrict__ P,
             const float* __restrict__ x, short* __restrict__ xb,
             int nE, int N, int degB, int n4) {
    __shared__ unsigned smem[RSD];   // 100KB, role-dependent view
    const int bid = blockIdx.x;
    const int chunk = (nE + NCH - 1) / NCH;

    if (bid < degB) {                       // ---- deg histogram ----
        float* s_deg = reinterpret_cast<float*>(smem);
        const int r = bid / NCH, b = bid % NCH;
        const int base = r * RSD;
        for (int i = threadIdx.x; i < RSD; i += 1024) s_deg[i] = 0.f;
        __syncthreads();
        const int e0 = b * chunk, e1 = min(e0 + chunk, nE);
        for (int e = e0 + (int)threadIdx.x; e < e1; e += 1024) {
            unsigned so = (unsigned)(src[e] - base);
            if (so < RSD) atomicAdd(&s_deg[so], w[e]);
        }
        __syncthreads();
        const int lim = min(RSD, N - base);
        for (int i = threadIdx.x; i < lim; i += 1024)
            degPart[(size_t)b * N + base + i] = s_deg[i];
        return;
    }
    if (bid < degB + NCH) {                 // ---- cnt histogram (whole N) ----
        unsigned* s_cnt2 = smem;
        const int b = bid - degB;
        const int pairsN = (N + 1) >> 1;
        for (int i = threadIdx.x; i < pairsN; i += 1024) s_cnt2[i] = 0u;
        __syncthreads();
        const int e0 = b * chunk, e1 = min(e0 + chunk, nE);
        for (int e = e0 + (int)threadIdx.x; e < e1; e += 1024) {
            unsigned d = (unsigned)dst[e];
            atomicAdd(&s_cnt2[d >> 1], 1u << ((d & 1) * 16));
        }
        __syncthreads();
        unsigned* cp32 = reinterpret_cast<unsigned*>(cntPart + (size_t)b * N);
        for (int i = threadIdx.x; i < pairsN; i += 1024) cp32[i] = s_cnt2[i];
        return;
    }
    // ---- prepack + x->bf16 ----
    int idx = (bid - degB - NCH) * 1024 + (int)threadIdx.x;
    if (idx < 12 * 4 * 64) {
        int lane = idx & 63;
        int kt = (idx >> 6) & 3;
        int nt = idx >> 8;
        int gate = (nt < 4) ? 0 : (nt < 8) ? 2 : 3;
        int h = (nt & 3) * 16 + (lane & 15);
        int fb = (lane >> 4) * 8;
        short8v v;
#pragma unroll
        for (int j = 0; j < 8; ++j)
            v[j] = f2bf(Wx[((size_t)(gate * 4 + kt) * 32 + fb + j) * 64 + h]);
        *(reinterpret_cast<short8v*>(P) + idx) = v;
        return;
    }
    int i = idx - 12 * 4 * 64;
    if (i >= n4) return;
    const float4 v = *reinterpret_cast<const float4*>(x + (size_t)i * 4);
    short4 rb;
    rb.x = f2bf(v.x); rb.y = f2bf(v.y); rb.z = f2bf(v.z); rb.w = f2bf(v.w);
    *reinterpret_cast<short4*>(xb + (size_t)i * 4) = rb;
}

// K2: scan (blocks 0..nbS-1, 2048 nodes each) -> B1 -> prefix+rowptr+offs
// -> B2 -> fill (all 192 blocks, 3 ranges x 64 chunks, LDS cursor).
__global__ __launch_bounds__(1024)
void k_scan_fill(const float* __restrict__ degPart,
                 const unsigned short* __restrict__ cntPart,
                 float* __restrict__ dinv, int* __restrict__ cnt,
                 int* __restrict__ rowptr, int* __restrict__ partials,
                 int* __restrict__ flag, int* __restrict__ offs,
                 const int* __restrict__ src, const int* __restrict__ dst,
                 const float* __restrict__ w, int2* __restrict__ entries,
                 int nE, int N) {
    __shared__ int smem[RSF];   // 80KB; scan phase uses [0..1023]
    const int t = threadIdx.x;
    const int bid = blockIdx.x;
    const int nbS = (N + 2047) / 2048;
    const int n0 = bid * 2048 + t * 2;

    // ---- phase 1: per-node reduce + block-local exclusive scan ----
    int c0 = 0, c1 = 0, ex = 0;
    if (bid < nbS) {
        float d0 = 0.f, d1 = 0.f;
        if (n0 < N) {
#pragma unroll 8
            for (int b = 0; b < NCH; ++b) {
                const float2 dv = *reinterpret_cast<const float2*>(degPart + (size_t)b * N + n0);
                d0 += dv.x; d1 += dv.y;
                unsigned cc = *reinterpret_cast<const unsigned*>(cntPart + (size_t)b * N + n0);
                c0 += (int)(cc & 0xFFFFu); c1 += (int)(cc >> 16);
            }
            dinv[n0] = d0 > 0.f ? rsqrtf(d0) : 0.f;
            cnt[n0] = c0;
            if (n0 + 1 < N) {
                dinv[n0 + 1] = d1 > 0.f ? rsqrtf(d1) : 0.f;
                cnt[n0 + 1] = c1;
            } else c1 = 0;
        }
        int cs = c0 + c1;
        smem[t] = cs;
        __syncthreads();
        for (int off = 1; off < 1024; off <<= 1) {
            int u = (t >= off) ? smem[t - off] : 0;
            __syncthreads();
            smem[t] += u;
            __syncthreads();
        }
        ex = smem[t] - cs;
        if (t == 1023)
            __hip_atomic_store(&partials[bid], smem[1023], __ATOMIC_RELEASE,
                               __HIP_MEMORY_SCOPE_AGENT);
    }
    gbar(flag, G2);

    // ---- phase 2: per-block prefix + rowptr + per-chunk offs ----
    if (bid < nbS) {
        int v = (t < bid) ? __hip_atomic_load(&partials[t], __ATOMIC_RELAXED,
                                              __HIP_MEMORY_SCOPE_AGENT)
                          : 0;
        smem[t] = v;
        __syncthreads();
        for (int off = 512; off > 0; off >>= 1) {
            if (t < off) smem[t] += smem[t + off];
            __syncthreads();
        }
        const int prefix = smem[0];
        if (n0 < N) {
            const bool has1 = (n0 + 1) < N;
            int s0 = ex + prefix;
            int s1 = has1 ? ex + c0 + prefix : 0;
            rowptr[n0] = s0;
            if (has1) rowptr[n0 + 1] = s1;
#pragma unroll 8
            for (int b = 0; b < NCH; ++b) {
                unsigned cc = *reinterpret_cast<const unsigned*>(cntPart + (size_t)b * N + n0);
                if (has1) {
                    *reinterpret_cast<int2*>(offs + (size_t)b * N + n0) = make_int2(s0, s1);
                } else {
                    offs[(size_t)b * N + n0] = s0;
                }
                s0 += (int)(cc & 0xFFFFu);
                s1 += (int)(cc >> 16);
            }
        }
    }
    gbar(flag, 2 * G2);

    // ---- phase 3: counting-sort fill ----
    const int r = bid / NCH, b = bid % NCH;
    const int base = r * RSF;
    const int lim = min(RSF, N - base);
    for (int i = t; i < lim; i += 1024)
        smem[i] = offs[(size_t)b * N + base + i];
    __syncthreads();
    const int chunk = (nE + NCH - 1) / NCH;
    const int e0 = b * chunk, e1 = min(e0 + chunk, nE);
    for (int e = e0 + t; e < e1; e += 1024) {
        int d = dst[e];
        unsigned dof = (unsigned)(d - base);
        if (dof < RSF) {
            int s = src[e];
            float nv = -dinv[s] * w[e] * dinv[d];
            int pos = atomicAdd(&smem[dof], 1);
            entries[pos] = make_int2(s, __float_as_int(nv));
        }
    }
}

__device__ __forceinline__ void bf8_fma(float* acc, ushort8v v, float s) {
#pragma unroll
    for (int j = 0; j < 8; ++j)
        acc[j] = fmaf(s, bf2f(v[j]), acc[j]);
}

// one gather work-item: 16 threads/node (tq feature-slice, qr entry-quarter)
__device__ __forceinline__ void gather_item(
    const unsigned short* __restrict__ tb, const unsigned short* __restrict__ subb,
    short* __restrict__ outb, const int* __restrict__ rowptr,
    const int* __restrict__ cnt, const int2* __restrict__ entries,
    float scale, int idx) {
    int n = idx >> 4, tq = idx & 3, qr = (idx >> 2) & 3;
    int beg = rowptr[n], end = beg + cnt[n];
    float acc0[8] = {0, 0, 0, 0, 0, 0, 0, 0};
    float acc1[8] = {0, 0, 0, 0, 0, 0, 0, 0};
    int i = beg + qr;
    for (; i + 12 < end; i += 16) {
        int2 e0 = entries[i];
        int2 e1 = entries[i + 4];
        int2 e2 = entries[i + 8];
        int2 e3 = entries[i + 12];
        ushort8v v0 = *reinterpret_cast<const ushort8v*>(tb + (size_t)e0.x * 32 + tq * 8);
        ushort8v v1 = *reinterpret_cast<const ushort8v*>(tb + (size_t)e1.x * 32 + tq * 8);
        ushort8v v2 = *reinterpret_cast<const ushort8v*>(tb + (size_t)e2.x * 32 + tq * 8);
        ushort8v v3 = *reinterpret_cast<const ushort8v*>(tb + (size_t)e3.x * 32 + tq * 8);
        bf8_fma(acc0, v0, __int_as_float(e0.y));
        bf8_fma(acc1, v1, __int_as_float(e1.y));
        bf8_fma(acc0, v2, __int_as_float(e2.y));
        bf8_fma(acc1, v3, __int_as_float(e3.y));
    }
    for (; i < end; i += 4) {
        int2 e0 = entries[i];
        ushort8v v0 = *reinterpret_cast<const ushort8v*>(tb + (size_t)e0.x * 32 + tq * 8);
        bf8_fma(acc0, v0, __int_as_float(e0.y));
    }
    float r[8];
#pragma unroll
    for (int j = 0; j < 8; ++j) {
        r[j] = acc0[j] + acc1[j];
        r[j] += __shfl_xor(r[j], 4);
        r[j] += __shfl_xor(r[j], 8);
    }
    if (qr == 0) {
        if (subb) {
            ushort8v sv = *reinterpret_cast<const ushort8v*>(subb + (size_t)n * 32 + tq * 8);
#pragma unroll
            for (int j = 0; j < 8; ++j) r[j] = fmaf(scale, r[j], -bf2f(sv[j]));
        } else {
#pragma unroll
            for (int j = 0; j < 8; ++j) r[j] *= scale;
        }
        short8v rb;
#pragma unroll
        for (int j = 0; j < 8; ++j) rb[j] = f2bf(r[j]);
        *reinterpret_cast<short8v*>(outb + (size_t)n * 32 + tq * 8) = rb;
    }
}

__device__ __forceinline__ float sigf(float x) {
    return __builtin_amdgcn_rcpf(1.f + __builtin_amdgcn_exp2f(-1.4426950408889634f * x));
}
__device__ __forceinline__ float tanhf_fast(float x) {
    float e = __builtin_amdgcn_exp2f(2.8853900817779268f * x);
    return 1.f - 2.f * __builtin_amdgcn_rcpf(e + 1.f);
}

// K3: gather1 -> B1 -> gather2 -> B2 -> fused gather3+MFMA+LSTM+head.
__global__ __launch_bounds__(NT3)
void k_gather_final(const short* __restrict__ xb, short* __restrict__ Tx1b,
                    short* __restrict__ Tx2b, const short* __restrict__ P,
                    const int* __restrict__ rowptr, const int* __restrict__ cnt,
                    const int2* __restrict__ entries,
                    const float* __restrict__ bx, const float* __restrict__ bh,
                    const float* __restrict__ wc, const float* __restrict__ bg,
                    const float* __restrict__ lin_w, const float* __restrict__ lin_b,
                    int* __restrict__ flag, float* __restrict__ out, int N) {
    const int stride = G3 * NT3;
    const int tid0 = blockIdx.x * NT3 + (int)threadIdx.x;
    const unsigned short* xbu = reinterpret_cast<const unsigned short*>(xb);

    // phase 1: Tx1b = prop(x)
    for (int idx = tid0; idx < N * 16; idx += stride)
        gather_item(xbu, nullptr, Tx1b, rowptr, cnt, entries, 1.f, idx);
    gbar(flag, G3);

    // phase 2: Tx2b = 2*prop(Tx1b) - x
    for (int idx = tid0; idx < N * 16; idx += stride)
        gather_item(reinterpret_cast<const unsigned short*>(Tx1b), xbu, Tx2b,
                    rowptr, cnt, entries, 2.f, idx);
    gbar(flag, 2 * G3);

    // phase 3: fused gather3 + MFMA gates + LSTM pointwise + linear head
    const int wave = (int)threadIdx.x >> 6, lane = (int)threadIdx.x & 63;
    const unsigned short* t2b = reinterpret_cast<const unsigned short*>(Tx2b);
    const int nTiles = (N + 127) / 128;
    for (int tile = blockIdx.x; tile < nTiles; tile += G3) {
        const int nb = tile * 128 + wave * 16;
        const int rc = min(nb + (lane & 15), N - 1);
        const int ko = (lane >> 4) * 8;

        int beg = rowptr[rc], end = beg + cnt[rc];
        float acc0[8] = {0, 0, 0, 0, 0, 0, 0, 0};
        float acc1[8] = {0, 0, 0, 0, 0, 0, 0, 0};
        int i = beg;
        for (; i + 3 < end; i += 4) {
            int2 e0 = entries[i];
            int2 e1 = entries[i + 1];
            int2 e2 = entries[i + 2];
            int2 e3 = entries[i + 3];
            ushort8v v0 = *reinterpret_cast<const ushort8v*>(t2b + (size_t)e0.x * 32 + ko);
            ushort8v v1 = *reinterpret_cast<const ushort8v*>(t2b + (size_t)e1.x * 32 + ko);
            ushort8v v2 = *reinterpret_cast<const ushort8v*>(t2b + (size_t)e2.x * 32 + ko);
            ushort8v v3 = *reinterpret_cast<const ushort8v*>(t2b + (size_t)e3.x * 32 + ko);
            bf8_fma(acc0, v0, __int_as_float(e0.y));
            bf8_fma(acc1, v1, __int_as_float(e1.y));
            bf8_fma(acc0, v2, __int_as_float(e2.y));
            bf8_fma(acc1, v3, __int_as_float(e3.y));
        }
        for (; i < end; ++i) {
            int2 e0 = entries[i];
            ushort8v v0 = *reinterpret_cast<const ushort8v*>(t2b + (size_t)e0.x * 32 + ko);
            bf8_fma(acc0, v0, __int_as_float(e0.y));
        }

        short8v A0 = *reinterpret_cast<const short8v*>(xb   + (size_t)rc * 32 + ko);
        short8v A1 = *reinterpret_cast<const short8v*>(Tx1b + (size_t)rc * 32 + ko);
        short8v A2 = *reinterpret_cast<const short8v*>(Tx2b + (size_t)rc * 32 + ko);
        short8v A3;
#pragma unroll
        for (int j = 0; j < 8; ++j)   // Tx3 = 2*prop(Tx2) - Tx1
            A3[j] = f2bf(2.f * (acc0[j] + acc1[j]) - bf2f((unsigned short)A1[j]));

        const short8v* Pv = reinterpret_cast<const short8v*>(P);
        f32x4 acc[12];
#pragma unroll
        for (int nt = 0; nt < 12; ++nt) {
            const short8v* Pb = Pv + (size_t)nt * 4 * 64 + lane;
            f32x4 a = {0.f, 0.f, 0.f, 0.f};
            a = __builtin_amdgcn_mfma_f32_16x16x32_bf16(A0, Pb[0],   a, 0, 0, 0);
            a = __builtin_amdgcn_mfma_f32_16x16x32_bf16(A1, Pb[64],  a, 0, 0, 0);
            a = __builtin_amdgcn_mfma_f32_16x16x32_bf16(A2, Pb[128], a, 0, 0, 0);
            a = __builtin_amdgcn_mfma_f32_16x16x32_bf16(A3, Pb[192], a, 0, 0, 0);
            acc[nt] = a;
        }

        const int hq = lane & 15;
        const int ng = lane >> 4;
        const float lb = lin_b[0];
        float p[4] = {0.f, 0.f, 0.f, 0.f};
#pragma unroll
        for (int ht = 0; ht < 4; ++ht) {
            int h = ht * 16 + hq;
            float bI = bx[h] + bh[h] + bg[h];
            float bC = bx[128 + h] + bh[128 + h] + bg[128 + h];
            float bO = bx[192 + h] + bh[192 + h] + bg[192 + h];
            float w2 = wc[128 + h];
            float lw = lin_w[h];
#pragma unroll
            for (int r = 0; r < 4; ++r) {
                float I = sigf(acc[ht][r] + bI);
                float T = tanhf_fast(acc[4 + ht][r] + bC);
                float C = I * T;
                float O = sigf(acc[8 + ht][r] + bO + w2 * C);
                float H = O * tanhf_fast(C);
                p[r] = fmaf(H, lw, p[r]);
            }
        }
#pragma unroll
        for (int r = 0; r < 4; ++r) {
            float v = p[r];
            v += __shfl_xor(v, 1);
            v += __shfl_xor(v, 2);
            v += __shfl_xor(v, 4);
            v += __shfl_xor(v, 8);
            if (hq == 0) {
                int n = nb + ng * 4 + r;
                if (n < N) out[n] = v + lb;
            }
        }
    }
}

extern "C" void kernel_launch(void* const* d_in, const int* in_sizes, int n_in,
                              void* d_out, int out_size, void* d_ws, size_t ws_size,
                              hipStream_t stream) {
    const float* x   = (const float*)d_in[0];
    const int*   ei  = (const int*)d_in[1];
    const float* ew  = (const float*)d_in[2];
    const float* Wx  = (const float*)d_in[3];
    const float* bx  = (const float*)d_in[4];
    // d_in[5] = Wh (unused: zero initial state)
    const float* bh  = (const float*)d_in[6];
    const float* wcp = (const float*)d_in[7];
    const float* bg  = (const float*)d_in[8];
    const float* lw  = (const float*)d_in[9];
    const float* lb  = (const float*)d_in[10];
    float* out = (float*)d_out;

    const int N  = in_sizes[0] / 32;
    const int nE = in_sizes[2];
    const int* src = ei;
    const int* dst = ei + nE;

    char* ws = (char*)d_ws;
    size_t off = 0;
    float* dinv    = (float*)(ws + off); off += (size_t)N * 4;
    int*   cnt     = (int*)(ws + off);   off += (size_t)N * 4;
    int*   rowptr  = (int*)(ws + off);   off += (size_t)N * 4;
    int*   partials= (int*)(ws + off);   off += 1024 * 4;
    int*   flags   = (int*)(ws + off);   off += 256;   // flags[0]=K2, flags[1]=K3
    short* P       = (short*)(ws + off); off += 12 * 4 * 64 * 8 * 2;
    int2*  entries = (int2*)(ws + off);  off += (size_t)nE * 8;
    float* degPart = (float*)(ws + off); off += (size_t)NCH * N * 4;  // aliased as offs
    unsigned short* cntPart = (unsigned short*)(ws + off); off += (size_t)NCH * N * 2;
    short* xbuf    = (short*)(ws + off); off += (size_t)N * 32 * 2;
    short* Tx1b    = (short*)(ws + off); off += (size_t)N * 32 * 2;
    short* Tx2b    = (short*)(ws + off); off += (size_t)N * 32 * 2;

    int* offs = (int*)degPart;  // degPart dead after K2 phase 1

    const int nRangeD = (N + RSD - 1) / RSD;
    const int degB = nRangeD * NCH;
    const int n4 = N * 8;
    const int xbB = (12 * 4 * 64 + n4 + 1023) / 1024;

    hipMemsetAsync(flags, 0, 8, stream);
    k_front<<<degB + NCH + xbB, 1024, 0, stream>>>(src, dst, ew, degPart, cntPart,
                                                   Wx, P, x, xbuf, nE, N, degB, n4);
    k_scan_fill<<<G2, 1024, 0, stream>>>(degPart, cntPart, dinv, cnt, rowptr,
                                         partials, &flags[0], offs, src, dst, ew,
                                         entries, nE, N);
    k_gather_final<<<G3, NT3, 0, stream>>>(xbuf, Tx1b, Tx2b, P, rowptr, cnt,
                                           entries, bx, bh, wcp, bg, lw, lb,
                                           &flags[1], out, N);
}